// Round 1
// baseline (251.947 us; speedup 1.0000x reference)
//
#include <hip/hip_runtime.h>

// FFLayer: out = relu( (x / (||x||_2 + 1e-4)) @ W^T + b )
// x: [131072, 1024] f32, W: [256, 1024] f32, b: [256] f32, out: [131072, 256] f32
//
// Strategy: bf16 MFMA GEMM (no fp32 MFMA on CDNA4). Normalization folded into
// epilogue: h = (x @ W^T) * inv_norm + b, with sum(x^2) accumulated during
// A-staging (single pass over x -> memory-bound floor ~107us).

#define IN_F   1024
#define OUT_F  256
#define BATCH  131072
#define BM     64
#define BK     64
#define NKT    (IN_F / BK)   // 16 K-steps
#define EPSV   1e-4f

typedef __attribute__((ext_vector_type(8))) __bf16 bf16x8;
typedef __attribute__((ext_vector_type(4))) __bf16 bf16x4;
typedef __attribute__((ext_vector_type(4))) float  f32x4;

__device__ __forceinline__ void gload_lds16(const void* g, void* lds) {
  __builtin_amdgcn_global_load_lds(
      (const __attribute__((address_space(1))) void*)g,
      (__attribute__((address_space(3))) void*)lds, 16, 0, 0);
}

// W (f32 [256][1024]) -> bf16 [256][1024] in d_ws (512 KB)
__global__ void wconv_kernel(const float* __restrict__ W, __bf16* __restrict__ Wb) {
  const int t = blockIdx.x * blockDim.x + threadIdx.x;   // 65536 threads, 4 elems each
  const float4 v = reinterpret_cast<const float4*>(W)[t];
  bf16x4 h;
  h[0] = (__bf16)v.x; h[1] = (__bf16)v.y; h[2] = (__bf16)v.z; h[3] = (__bf16)v.w;
  reinterpret_cast<bf16x4*>(Wb)[t] = h;
}

__global__ __launch_bounds__(512, 4)
void ffl_kernel(const float* __restrict__ x, const __bf16* __restrict__ Wb,
                const float* __restrict__ bias, float* __restrict__ out) {
  // LDS: 2*8KB (A) + 2*32KB (B) = 80 KB -> exactly 2 blocks/CU (160 KB)
  __shared__ __bf16 Ab[2][BM * BK];
  __shared__ __bf16 Bb[2][OUT_F * BK];

  const int tid  = threadIdx.x;
  const int lane = tid & 63;
  const int wave = tid >> 6;     // 8 waves
  const int wr   = wave >> 2;    // 0..1 (M)
  const int wc   = wave & 3;     // 0..3 (N)
  const size_t block_row = (size_t)blockIdx.x * BM;

  // ---- A staging coords: thread stages row ar, granule ag (8 f32 = 16B bf16)
  const int ar = tid >> 3;       // 0..63 (same row every K-step -> per-thread sumsq)
  const int ag = tid & 7;
  const float* xp = x + (block_row + ar) * IN_F + ag * 8;
  const int a_byte = ar * 128 + ((ag * 16) ^ ((ar & 7) << 4));   // XOR-swizzled dest

  // ---- B staging coords: global_load_lds, linear LDS dest, pre-swizzled source
  const int sr = lane >> 3;      // row within 8-row chunk (== n&7)
  const int sg = lane & 7;       // 16B granule within 128B row
  const int b_src_off = (sg * 16) ^ (sr << 4);

  f32x4 acc[2][4];
  #pragma unroll
  for (int m = 0; m < 2; ++m)
    #pragma unroll
    for (int n = 0; n < 4; ++n)
      acc[m][n] = (f32x4){0.f, 0.f, 0.f, 0.f};

  float sumsq = 0.f;
  const char* WbB = (const char*)Wb;

  auto stage = [&](int buf, int kt) {
    // B tile: 256x64 bf16 = 32KB, 4 x global_load_lds(16B) per thread
    #pragma unroll
    for (int c = 0; c < 4; ++c) {
      const int ci = wave * 4 + c;           // 1KB chunk index (8 rows)
      const int n  = ci * 8 + sr;            // W row (output col)
      gload_lds16(WbB + (size_t)n * (IN_F * 2) + kt * (BK * 2) + b_src_off,
                  (void*)&Bb[buf][ci * 512]);
    }
    // A tile: load 8 f32, accumulate sumsq (f32), convert, swizzled ds_write_b128
    const float4 lo = *(const float4*)(xp + kt * BK);
    const float4 hi = *(const float4*)(xp + kt * BK + 4);
    sumsq += lo.x*lo.x + lo.y*lo.y + lo.z*lo.z + lo.w*lo.w
           + hi.x*hi.x + hi.y*hi.y + hi.z*hi.z + hi.w*hi.w;
    bf16x8 h;
    h[0]=(__bf16)lo.x; h[1]=(__bf16)lo.y; h[2]=(__bf16)lo.z; h[3]=(__bf16)lo.w;
    h[4]=(__bf16)hi.x; h[5]=(__bf16)hi.y; h[6]=(__bf16)hi.z; h[7]=(__bf16)hi.w;
    *reinterpret_cast<bf16x8*>((char*)Ab[buf] + a_byte) = h;
  };

  stage(0, 0);
  __syncthreads();

  const int rm = lane & 15;
  const int kq = (lane >> 4) * 16;   // 16B k-granule per lane quarter

  for (int kt = 0; kt < NKT; ++kt) {
    const int cur = kt & 1;
    if (kt + 1 < NKT) stage(cur ^ 1, kt + 1);   // prefetch next tile

    // A fragments: rows wr*32 + m*16 + rm, k-granule kk*64 + kq (swizzled)
    bf16x8 aF[2][2];
    #pragma unroll
    for (int m = 0; m < 2; ++m) {
      const int ra = wr * 32 + m * 16 + rm;
      const char* abase = (const char*)Ab[cur] + ra * 128;
      const int sw = (ra & 7) << 4;
      #pragma unroll
      for (int kk = 0; kk < 2; ++kk)
        aF[m][kk] = *reinterpret_cast<const bf16x8*>(abase + ((kk * 64 + kq) ^ sw));
    }
    #pragma unroll
    for (int n = 0; n < 4; ++n) {
      const int rb = wc * 64 + n * 16 + rm;
      const char* bbase = (const char*)Bb[cur] + rb * 128;
      const int sw = (rb & 7) << 4;
      #pragma unroll
      for (int kk = 0; kk < 2; ++kk) {
        const bf16x8 bF = *reinterpret_cast<const bf16x8*>(bbase + ((kk * 64 + kq) ^ sw));
        #pragma unroll
        for (int m = 0; m < 2; ++m)
          acc[m][n] = __builtin_amdgcn_mfma_f32_16x16x32_bf16(aF[m][kk], bF, acc[m][n], 0, 0, 0);
      }
    }
    __syncthreads();
  }

  // ---- row L2-norm: reduce sumsq across the 8 staging threads of each row
  sumsq += __shfl_xor(sumsq, 1);
  sumsq += __shfl_xor(sumsq, 2);
  sumsq += __shfl_xor(sumsq, 4);
  float* norms = reinterpret_cast<float*>(Ab[0]);   // Ab free after K loop
  if (ag == 0) norms[ar] = 1.0f / (sqrtf(sumsq) + EPSV);
  __syncthreads();

  // ---- epilogue: scale by inv_norm, +bias, relu, store
  const int col0 = wc * 64 + rm;
  #pragma unroll
  for (int n = 0; n < 4; ++n) {
    const float bn = bias[col0 + n * 16];
    #pragma unroll
    for (int m = 0; m < 2; ++m) {
      #pragma unroll
      for (int j = 0; j < 4; ++j) {
        const int lr = wr * 32 + m * 16 + (lane >> 4) * 4 + j;
        const float v = fmaxf(acc[m][n][j] * norms[lr] + bn, 0.f);
        out[(block_row + lr) * OUT_F + col0 + n * 16] = v;
      }
    }
  }
}

extern "C" void kernel_launch(void* const* d_in, const int* in_sizes, int n_in,
                              void* d_out, int out_size, void* d_ws, size_t ws_size,
                              hipStream_t stream) {
  const float* x = (const float*)d_in[0];
  const float* W = (const float*)d_in[1];
  const float* b = (const float*)d_in[2];
  float* out = (float*)d_out;
  __bf16* Wb = (__bf16*)d_ws;   // needs 512 KB scratch

  wconv_kernel<<<(OUT_F * IN_F / 4) / 256, 256, 0, stream>>>(W, Wb);
  ffl_kernel<<<BATCH / BM, 512, 0, stream>>>(x, Wb, b, out);
}